// Round 3
// baseline (184.206 us; speedup 1.0000x reference)
//
#include <hip/hip_runtime.h>
#include <hip/hip_cooperative_groups.h>

namespace cg = cooperative_groups;

typedef short short8  __attribute__((ext_vector_type(8)));
typedef short short4v __attribute__((ext_vector_type(4)));
typedef float f32x4   __attribute__((ext_vector_type(4)));

static __device__ __forceinline__ unsigned short f2bf(float f) {
  unsigned int u = __builtin_bit_cast(unsigned int, f);
  u += 0x7fffu + ((u >> 16) & 1u);   // RNE
  return (unsigned short)(u >> 16);
}
static __device__ __forceinline__ float bf2f(unsigned short u) {
  unsigned int v = ((unsigned int)u) << 16;
  return __builtin_bit_cast(float, v);
}
// pack two f32 -> two bf16 (RTZ) in ONE v_perm_b32: D = [hi.b3 hi.b2 lo.b3 lo.b2]
static __device__ __forceinline__ unsigned int pack2bf_rtz(float lo, float hi) {
  return __builtin_amdgcn_perm(__builtin_bit_cast(unsigned int, hi),
                               __builtin_bit_cast(unsigned int, lo), 0x07060302u);
}

// ---------------------------------------------------------------------------
// Single cooperative kernel, grid 64x4 blocks of 512 threads (8 waves/block,
// 1 block/CU).
//
// Phase 1 (QKV for own n-slice): block (qg,b) computes Q/K/V for
// n in [qg*64, qg*64+64).  Wave w handles n-subslice (w&3) and rt tiles
// {(w>>2), (w>>2)+2, (w>>2)+4}  (waves 0-3: Q,V0,V2; waves 4-7: K,V1,V3),
// so each wave loads its x-slice ONCE (x HBM traffic 24MB -> 4MB vs the old
// 6-pass qkv kernel).  Q (pre-scaled by log2e) goes to LDS only -- never to
// global.  K -> bf16 [b][n][16], V -> bf16 [b][c][n] in workspace.
//
// grid.sync() (cooperative) makes kb/vb visible across XCDs.
//
// Phase 2 (flash + combine): identical to the previous round's proven
// pipeline: 8 waves = 8 j-splits for the block's 64-query group; barrier-free
// software-pipelined j-loop (vf under S/exp, next kf under PV), raw
// v_exp_f32, setprio(1) around PV MFMAs, per-wave swizzled P LDS; O-partials
// bf16 (RNE) into own LDS slot (XOR-swizzled rows), in-block f32 combine,
// l-exchange through freed LDS, gamma*O + x with T14-early x loads.
// Static LDS = exactly 64 KB.
// ---------------------------------------------------------------------------
__global__ __launch_bounds__(512) void fused_all(
    const float* __restrict__ x,
    const float* __restrict__ Wq, const float* __restrict__ bq,
    const float* __restrict__ Wk, const float* __restrict__ bk,
    const float* __restrict__ Wv, const float* __restrict__ bv,
    unsigned short* __restrict__ kb, unsigned short* __restrict__ vb,
    const float* __restrict__ gptr, float* __restrict__ out)
{
  __shared__ unsigned short p_lds[8 * 4096];   // per-wave 8 KB slot (phase 2);
                                               // first 2 KB double as Q staging
  const int qg   = blockIdx.x;          // 0..63 (64-query / n-slice group)
  const int b    = blockIdx.y;          // 0..3
  const int t    = threadIdx.x;
  const int wave = t >> 6;              // 0..7
  const int lane = t & 63;
  const int l15  = lane & 15;
  const int quad = lane >> 4;
  const int sw   = l15 & 7;

  // ======================= Phase 1: QKV projection =========================
  {
    const int slice = wave & 3;                 // n-subslice 0..3
    const int n     = qg * 64 + slice * 16 + l15;

    short8 bfrag[2];
#pragma unroll
    for (int ks = 0; ks < 2; ++ks)
#pragma unroll
      for (int jj = 0; jj < 8; ++jj) {
        const int c = ks * 32 + quad * 8 + jj;
        bfrag[ks][jj] = (short)f2bf(x[((size_t)(b * 64 + c)) * 4096 + n]);
      }

#pragma unroll
    for (int rr = 0; rr < 3; ++rr) {
      const int rt = (wave >> 2) + rr * 2;      // waves 0-3: 0,2,4; 4-7: 1,3,5
      const float* wbase; const float* bias; int row0;
      if (rt == 0)      { wbase = Wq; bias = bq; row0 = 0; }
      else if (rt == 1) { wbase = Wk; bias = bk; row0 = 0; }
      else              { wbase = Wv; bias = bv; row0 = (rt - 2) * 16; }

      short8 afrag[2];
#pragma unroll
      for (int ks = 0; ks < 2; ++ks) {
        f32x4 w0 = *(const f32x4*)(wbase + (row0 + l15) * 64 + ks * 32 + quad * 8);
        f32x4 w1 = *(const f32x4*)(wbase + (row0 + l15) * 64 + ks * 32 + quad * 8 + 4);
#pragma unroll
        for (int jj = 0; jj < 4; ++jj) {
          afrag[ks][jj]     = (short)f2bf(w0[jj]);
          afrag[ks][jj + 4] = (short)f2bf(w1[jj]);
        }
      }

      f32x4 acc;
#pragma unroll
      for (int r = 0; r < 4; ++r)
        acc[r] = bias[row0 + quad * 4 + r];
      acc = __builtin_amdgcn_mfma_f32_16x16x32_bf16(afrag[0], bfrag[0], acc, 0, 0, 0);
      acc = __builtin_amdgcn_mfma_f32_16x16x32_bf16(afrag[1], bfrag[1], acc, 0, 0, 0);

      if (rt == 0) {
#pragma unroll
        for (int r = 0; r < 4; ++r) acc[r] *= 1.44269504088896340736f;  // log2(e)
        short4v sv;
#pragma unroll
        for (int r = 0; r < 4; ++r) sv[r] = (short)f2bf(acc[r]);
        // Q -> LDS only: [q64][d16] bf16, block-local
        *(short4v*)(p_lds + (slice * 16 + l15) * 16 + quad * 4) = sv;
      } else if (rt == 1) {
        short4v sv;
#pragma unroll
        for (int r = 0; r < 4; ++r) sv[r] = (short)f2bf(acc[r]);
        *(short4v*)(kb + (((size_t)b * 4096 + n) * 16) + quad * 4) = sv;
      } else {
#pragma unroll
        for (int r = 0; r < 4; ++r) {
          const int c = row0 + quad * 4 + r;
          vb[((size_t)(b * 64 + c)) * 4096 + n] = f2bf(acc[r]);
        }
      }
    }
  }
  __syncthreads();

  // qfrag from LDS (block computed its own Q in phase 1)
  short8 qfrag[4];
#pragma unroll
  for (int qt = 0; qt < 4; ++qt) {
    qfrag[qt] = (short8)0;
    if (quad < 2)
      qfrag[qt] = *(const short8*)(p_lds + (qt * 16 + l15) * 16 + quad * 8);
  }

  // grid-wide sync: kb/vb (written by all blocks) become visible; also orders
  // the qfrag LDS reads before phase 2's p_lds overwrites.
  __threadfence();
  cg::this_grid().sync();
  __threadfence();

  // ======================= Phase 2: flash + combine ========================
  const unsigned short* vbb = vb + (size_t)b * 64 * 4096;
  const unsigned short* kbb = kb + (size_t)b * 4096 * 16;
  f32x4 acc[4][4];
#pragma unroll
  for (int qt = 0; qt < 4; ++qt)
#pragma unroll
    for (int ct = 0; ct < 4; ++ct) acc[qt][ct] = (f32x4)0.f;
  float lp[4] = {0.f, 0.f, 0.f, 0.f};
  unsigned short* pw = p_lds + wave * 4096;

  const int jbeg = wave * 512;
  const int jend = jbeg + 512;

  short8 kf[4];
#pragma unroll
  for (int sub = 0; sub < 4; ++sub) {
    kf[sub] = (short8)0;
    if (quad < 2)
      kf[sub] = *(const short8*)(kbb + (size_t)(jbeg + sub * 16 + l15) * 16 + quad * 8);
  }

#pragma unroll 1
  for (int j0 = jbeg; j0 < jend; j0 += 64) {
    short8 vf[2][4];
#pragma unroll
    for (int kc = 0; kc < 2; ++kc) {
      const int vcol = j0 + kc * 32 + quad * 8;
#pragma unroll
      for (int ct = 0; ct < 4; ++ct)
        vf[kc][ct] = *(const short8*)(vbb + (size_t)(ct * 16 + l15) * 4096 + vcol);
    }

#pragma unroll
    for (int qt = 0; qt < 4; ++qt) {
#pragma unroll
      for (int sub = 0; sub < 4; ++sub) {
        f32x4 sc = __builtin_amdgcn_mfma_f32_16x16x32_bf16(kf[sub], qfrag[qt], (f32x4)0.f, 0, 0, 0);
        float p0 = __builtin_amdgcn_exp2f(sc[0]);
        float p1 = __builtin_amdgcn_exp2f(sc[1]);
        float p2 = __builtin_amdgcn_exp2f(sc[2]);
        float p3 = __builtin_amdgcn_exp2f(sc[3]);
        lp[qt] += (p0 + p1) + (p2 + p3);
        const int ch = (sub * 2 + (quad >> 1)) ^ sw;
        unsigned int* dst = (unsigned int*)(pw + (qt * 16 + l15) * 64 + ch * 8 + (quad & 1) * 4);
        dst[0] = pack2bf_rtz(p0, p1);
        dst[1] = pack2bf_rtz(p2, p3);
      }
    }

    short8 kfn[4];
    const int jn = j0 + 64;
    const bool more = (jn < jend);
#pragma unroll
    for (int sub = 0; sub < 4; ++sub) {
      kfn[sub] = (short8)0;
      if (more && quad < 2)
        kfn[sub] = *(const short8*)(kbb + (size_t)(jn + sub * 16 + l15) * 16 + quad * 8);
    }

    __builtin_amdgcn_s_setprio(1);
#pragma unroll
    for (int kc = 0; kc < 2; ++kc) {
#pragma unroll
      for (int qt = 0; qt < 4; ++qt) {
        short8 pf = *(const short8*)(pw + (qt * 16 + l15) * 64 + ((kc * 4 + quad) ^ sw) * 8);
#pragma unroll
        for (int ct = 0; ct < 4; ++ct)
          acc[qt][ct] = __builtin_amdgcn_mfma_f32_16x16x32_bf16(vf[kc][ct], pf, acc[qt][ct], 0, 0, 0);
      }
    }
    __builtin_amdgcn_s_setprio(0);

#pragma unroll
    for (int sub = 0; sub < 4; ++sub) kf[sub] = kfn[sub];
  }

  // issue residual x loads NOW so they overlap the whole LDS combine (T14)
  float xr[8];
#pragma unroll
  for (int r = 0; r < 8; ++r) {
    const int c = wave * 8 + r;
    xr[r] = x[((size_t)(b * 64 + c)) * 4096 + (size_t)qg * 64 + lane];
  }

  // full row-sums of l for q = qt*16 + l15 (sum the 4 quads)
#pragma unroll
  for (int qt = 0; qt < 4; ++qt) {
    lp[qt] += __shfl_xor(lp[qt], 16);
    lp[qt] += __shfl_xor(lp[qt], 32);
  }

  // O-partial -> own LDS slot, [q64][c64] bf16 (RNE), 16B-block XOR swizzle.
#pragma unroll
  for (int qt = 0; qt < 4; ++qt)
#pragma unroll
    for (int ct = 0; ct < 4; ++ct) {
      short4v sv;
#pragma unroll
      for (int r = 0; r < 4; ++r) sv[r] = (short)f2bf(acc[qt][ct][r]);
      const int q = qt * 16 + l15;
      const unsigned off = (unsigned)(q * 128 + (ct * 16 + quad * 4) * 2)
                         ^ (unsigned)((q & 7) << 4);
      *(short4v*)((char*)pw + off) = sv;
    }
  __syncthreads();

  // combine: thread (qq=lane, cblk=wave) sums slots' [qq][cblk*8..+7] in f32
  float o[8] = {0.f, 0.f, 0.f, 0.f, 0.f, 0.f, 0.f, 0.f};
  const unsigned roff = (unsigned)(lane * 128 + wave * 16)
                      ^ (unsigned)((lane & 7) << 4);
#pragma unroll
  for (int w = 0; w < 8; ++w) {
    short8 v = *(const short8*)((const char*)(p_lds + w * 4096) + roff);
#pragma unroll
    for (int r = 0; r < 8; ++r) o[r] += bf2f((unsigned short)v[r]);
  }
  __syncthreads();

  // exchange l through the (now free) LDS
  float* lf = (float*)p_lds;
  if (lane < 16) {
#pragma unroll
    for (int qt = 0; qt < 4; ++qt)
      lf[wave * 64 + qt * 16 + lane] = lp[qt];
  }
  __syncthreads();
  float lsum = 0.f;
#pragma unroll
  for (int w = 0; w < 8; ++w) lsum += lf[w * 64 + lane];
  const float li = 1.f / lsum;
  const float g  = gptr[0];

  // out[(b*64+c)*4096 + qg*64 + qq]: lanes vary qq -> 256B coalesced stores
#pragma unroll
  for (int r = 0; r < 8; ++r) {
    const int c = wave * 8 + r;
    const size_t off = ((size_t)(b * 64 + c)) * 4096 + (size_t)qg * 64 + lane;
    out[off] = g * (o[r] * li) + xr[r];
  }
}

// ---------------------------------------------------------------------------
extern "C" void kernel_launch(void* const* d_in, const int* in_sizes, int n_in,
                              void* d_out, int out_size, void* d_ws, size_t ws_size,
                              hipStream_t stream)
{
  const float* x  = (const float*)d_in[0];
  const float* Wq = (const float*)d_in[1];
  const float* bq = (const float*)d_in[2];
  const float* Wk = (const float*)d_in[3];
  const float* bk = (const float*)d_in[4];
  const float* Wv = (const float*)d_in[5];
  const float* bv = (const float*)d_in[6];
  const float* g  = (const float*)d_in[7];

  unsigned short* ws = (unsigned short*)d_ws;
  unsigned short* kb = ws;                 // 4*4096*16 bf16 = 512 KB
  unsigned short* vb = ws + 262144;        // 4*64*4096 bf16 = 2 MB
  float* ob = (float*)d_out;

  void* args[] = {
    (void*)&x, (void*)&Wq, (void*)&bq, (void*)&Wk, (void*)&bk,
    (void*)&Wv, (void*)&bv, (void*)&kb, (void*)&vb, (void*)&g, (void*)&ob
  };
  hipLaunchCooperativeKernel((const void*)fused_all, dim3(64, 4), dim3(512),
                             args, 0, stream);
}

// Round 4
// 95.683 us; speedup vs baseline: 1.9252x; 1.9252x over previous
//
#include <hip/hip_runtime.h>

typedef short short8  __attribute__((ext_vector_type(8)));
typedef short short4v __attribute__((ext_vector_type(4)));
typedef float f32x4   __attribute__((ext_vector_type(4)));

static __device__ __forceinline__ unsigned short f2bf(float f) {
  unsigned int u = __builtin_bit_cast(unsigned int, f);
  u += 0x7fffu + ((u >> 16) & 1u);   // RNE
  return (unsigned short)(u >> 16);
}
static __device__ __forceinline__ float bf2f(unsigned short u) {
  unsigned int v = ((unsigned int)u) << 16;
  return __builtin_bit_cast(float, v);
}
// pack two f32 -> two bf16 (RTZ) in ONE v_perm_b32: D = [hi.b3 hi.b2 lo.b3 lo.b2]
static __device__ __forceinline__ unsigned int pack2bf_rtz(float lo, float hi) {
  return __builtin_amdgcn_perm(__builtin_bit_cast(unsigned int, hi),
                               __builtin_bit_cast(unsigned int, lo), 0x07060302u);
}

// ---------------------------------------------------------------------------
// Kernel 1: QKV projection, ONE x-pass (grid 64x4, 512 threads, 8 waves).
// Block (qg,b) computes Q/K/V for n in [qg*64, qg*64+64).  Wave w handles
// n-subslice (w&3) and rt tiles {(w>>2), (w>>2)+2, (w>>2)+4}  (waves 0-3:
// Q,V0,V2; waves 4-7: K,V1,V3), so each wave loads its x-slice ONCE:
// x HBM/L3 read traffic drops 24MB -> 4MB vs the old 6-pass rt-split kernel,
// and launch shrinks 1536 -> 256 blocks.  (NO grid sync here -- round 3
// showed cg::grid.sync costs ~90us; separate launch is ~3us.)
// rt0=Q (PRE-SCALED by log2(e)) -> bf16 [b][n][16]; K same; V -> [b][c][n].
// ---------------------------------------------------------------------------
__global__ __launch_bounds__(512) void qkv_onepass(
    const float* __restrict__ x,
    const float* __restrict__ Wq, const float* __restrict__ bq,
    const float* __restrict__ Wk, const float* __restrict__ bk,
    const float* __restrict__ Wv, const float* __restrict__ bv,
    unsigned short* __restrict__ qb, unsigned short* __restrict__ kb,
    unsigned short* __restrict__ vb)
{
  const int qg   = blockIdx.x;          // 0..63 (n-slice group)
  const int b    = blockIdx.y;          // 0..3
  const int t    = threadIdx.x;
  const int wave = t >> 6;              // 0..7
  const int lane = t & 63;
  const int l15  = lane & 15;
  const int quad = lane >> 4;

  const int slice = wave & 3;           // n-subslice 0..3
  const int n     = qg * 64 + slice * 16 + l15;

  short8 bfrag[2];
#pragma unroll
  for (int ks = 0; ks < 2; ++ks)
#pragma unroll
    for (int jj = 0; jj < 8; ++jj) {
      const int c = ks * 32 + quad * 8 + jj;
      bfrag[ks][jj] = (short)f2bf(x[((size_t)(b * 64 + c)) * 4096 + n]);
    }

#pragma unroll
  for (int rr = 0; rr < 3; ++rr) {
    const int rt = (wave >> 2) + rr * 2;        // waves 0-3: 0,2,4; 4-7: 1,3,5
    const float* wbase; const float* bias; int row0;
    if (rt == 0)      { wbase = Wq; bias = bq; row0 = 0; }
    else if (rt == 1) { wbase = Wk; bias = bk; row0 = 0; }
    else              { wbase = Wv; bias = bv; row0 = (rt - 2) * 16; }

    short8 afrag[2];
#pragma unroll
    for (int ks = 0; ks < 2; ++ks) {
      f32x4 w0 = *(const f32x4*)(wbase + (row0 + l15) * 64 + ks * 32 + quad * 8);
      f32x4 w1 = *(const f32x4*)(wbase + (row0 + l15) * 64 + ks * 32 + quad * 8 + 4);
#pragma unroll
      for (int jj = 0; jj < 4; ++jj) {
        afrag[ks][jj]     = (short)f2bf(w0[jj]);
        afrag[ks][jj + 4] = (short)f2bf(w1[jj]);
      }
    }

    f32x4 acc;
#pragma unroll
    for (int r = 0; r < 4; ++r)
      acc[r] = bias[row0 + quad * 4 + r];
    acc = __builtin_amdgcn_mfma_f32_16x16x32_bf16(afrag[0], bfrag[0], acc, 0, 0, 0);
    acc = __builtin_amdgcn_mfma_f32_16x16x32_bf16(afrag[1], bfrag[1], acc, 0, 0, 0);

    if (rt <= 1) {
      if (rt == 0) {
#pragma unroll
        for (int r = 0; r < 4; ++r) acc[r] *= 1.44269504088896340736f;  // log2(e)
      }
      short4v sv;
#pragma unroll
      for (int r = 0; r < 4; ++r) sv[r] = (short)f2bf(acc[r]);
      unsigned short* dst = (rt == 0 ? qb : kb);
      *(short4v*)(dst + (((size_t)b * 4096 + n) * 16) + quad * 4) = sv;
    } else {
#pragma unroll
      for (int r = 0; r < 4; ++r) {
        const int c = row0 + quad * 4 + r;
        vb[((size_t)(b * 64 + c)) * 4096 + n] = f2bf(acc[r]);
      }
    }
  }
}

// ---------------------------------------------------------------------------
// Kernel 2: FUSED flash + combine (byte-identical to the round-2 96us
// version).  Grid 64x4 blocks of 512 threads (8 waves).  8 waves = 8
// j-splits for one 64-query group; barrier-free software-pipelined j-loop
// (vf under S/exp, next kf under PV); raw v_exp_f32 (Q pre-scaled, tiny
// scores -> in-range); setprio(1) around PV MFMAs (T5); per-wave swizzled
// P LDS; O-partials bf16 (RNE) in own XOR-swizzled LDS slot; in-block f32
// combine; l through freed LDS; gamma*O + x with T14-early x loads.
// Static LDS = 64 KB.
// ---------------------------------------------------------------------------
__global__ __launch_bounds__(512) void flash_fused(
    const unsigned short* __restrict__ qb, const unsigned short* __restrict__ kb,
    const unsigned short* __restrict__ vb,
    const float* __restrict__ x, const float* __restrict__ gptr,
    float* __restrict__ out)
{
  __shared__ unsigned short p_lds[8 * 4096];   // per-wave 8 KB slot

  const int qg   = blockIdx.x;          // 0..63 (64-query group)
  const int b    = blockIdx.y;          // 0..3
  const int t    = threadIdx.x;
  const int wave = t >> 6;              // 0..7 == j-split index
  const int lane = t & 63;
  const int l15  = lane & 15;
  const int quad = lane >> 4;
  const int sw   = l15 & 7;

  short8 qfrag[4];
#pragma unroll
  for (int qt = 0; qt < 4; ++qt) {
    qfrag[qt] = (short8)0;
    if (quad < 2) {
      const int iq = qg * 64 + qt * 16 + l15;
      qfrag[qt] = *(const short8*)(qb + (((size_t)b * 4096 + iq) * 16 + quad * 8));
    }
  }

  const unsigned short* vbb = vb + (size_t)b * 64 * 4096;
  const unsigned short* kbb = kb + (size_t)b * 4096 * 16;
  f32x4 acc[4][4];
#pragma unroll
  for (int qt = 0; qt < 4; ++qt)
#pragma unroll
    for (int ct = 0; ct < 4; ++ct) acc[qt][ct] = (f32x4)0.f;
  float lp[4] = {0.f, 0.f, 0.f, 0.f};
  unsigned short* pw = p_lds + wave * 4096;

  const int jbeg = wave * 512;
  const int jend = jbeg + 512;

  short8 kf[4];
#pragma unroll
  for (int sub = 0; sub < 4; ++sub) {
    kf[sub] = (short8)0;
    if (quad < 2)
      kf[sub] = *(const short8*)(kbb + (size_t)(jbeg + sub * 16 + l15) * 16 + quad * 8);
  }

#pragma unroll 1
  for (int j0 = jbeg; j0 < jend; j0 += 64) {
    short8 vf[2][4];
#pragma unroll
    for (int kc = 0; kc < 2; ++kc) {
      const int vcol = j0 + kc * 32 + quad * 8;
#pragma unroll
      for (int ct = 0; ct < 4; ++ct)
        vf[kc][ct] = *(const short8*)(vbb + (size_t)(ct * 16 + l15) * 4096 + vcol);
    }

#pragma unroll
    for (int qt = 0; qt < 4; ++qt) {
#pragma unroll
      for (int sub = 0; sub < 4; ++sub) {
        f32x4 sc = __builtin_amdgcn_mfma_f32_16x16x32_bf16(kf[sub], qfrag[qt], (f32x4)0.f, 0, 0, 0);
        float p0 = __builtin_amdgcn_exp2f(sc[0]);
        float p1 = __builtin_amdgcn_exp2f(sc[1]);
        float p2 = __builtin_amdgcn_exp2f(sc[2]);
        float p3 = __builtin_amdgcn_exp2f(sc[3]);
        lp[qt] += (p0 + p1) + (p2 + p3);
        const int ch = (sub * 2 + (quad >> 1)) ^ sw;
        unsigned int* dst = (unsigned int*)(pw + (qt * 16 + l15) * 64 + ch * 8 + (quad & 1) * 4);
        dst[0] = pack2bf_rtz(p0, p1);
        dst[1] = pack2bf_rtz(p2, p3);
      }
    }

    short8 kfn[4];
    const int jn = j0 + 64;
    const bool more = (jn < jend);
#pragma unroll
    for (int sub = 0; sub < 4; ++sub) {
      kfn[sub] = (short8)0;
      if (more && quad < 2)
        kfn[sub] = *(const short8*)(kbb + (size_t)(jn + sub * 16 + l15) * 16 + quad * 8);
    }

    __builtin_amdgcn_s_setprio(1);
#pragma unroll
    for (int kc = 0; kc < 2; ++kc) {
#pragma unroll
      for (int qt = 0; qt < 4; ++qt) {
        short8 pf = *(const short8*)(pw + (qt * 16 + l15) * 64 + ((kc * 4 + quad) ^ sw) * 8);
#pragma unroll
        for (int ct = 0; ct < 4; ++ct)
          acc[qt][ct] = __builtin_amdgcn_mfma_f32_16x16x32_bf16(vf[kc][ct], pf, acc[qt][ct], 0, 0, 0);
      }
    }
    __builtin_amdgcn_s_setprio(0);

#pragma unroll
    for (int sub = 0; sub < 4; ++sub) kf[sub] = kfn[sub];
  }

  // issue residual x loads NOW so they overlap the whole LDS combine (T14)
  float xr[8];
#pragma unroll
  for (int r = 0; r < 8; ++r) {
    const int c = wave * 8 + r;
    xr[r] = x[((size_t)(b * 64 + c)) * 4096 + (size_t)qg * 64 + lane];
  }

  // full row-sums of l for q = qt*16 + l15 (sum the 4 quads)
#pragma unroll
  for (int qt = 0; qt < 4; ++qt) {
    lp[qt] += __shfl_xor(lp[qt], 16);
    lp[qt] += __shfl_xor(lp[qt], 32);
  }

  // O-partial -> own LDS slot, [q64][c64] bf16 (RNE), 16B-block XOR swizzle.
#pragma unroll
  for (int qt = 0; qt < 4; ++qt)
#pragma unroll
    for (int ct = 0; ct < 4; ++ct) {
      short4v sv;
#pragma unroll
      for (int r = 0; r < 4; ++r) sv[r] = (short)f2bf(acc[qt][ct][r]);
      const int q = qt * 16 + l15;
      const unsigned off = (unsigned)(q * 128 + (ct * 16 + quad * 4) * 2)
                         ^ (unsigned)((q & 7) << 4);
      *(short4v*)((char*)pw + off) = sv;
    }
  __syncthreads();

  // combine: thread (qq=lane, cblk=wave) sums slots' [qq][cblk*8..+7] in f32
  float o[8] = {0.f, 0.f, 0.f, 0.f, 0.f, 0.f, 0.f, 0.f};
  const unsigned roff = (unsigned)(lane * 128 + wave * 16)
                      ^ (unsigned)((lane & 7) << 4);
#pragma unroll
  for (int w = 0; w < 8; ++w) {
    short8 v = *(const short8*)((const char*)(p_lds + w * 4096) + roff);
#pragma unroll
    for (int r = 0; r < 8; ++r) o[r] += bf2f((unsigned short)v[r]);
  }
  __syncthreads();

  // exchange l through the (now free) LDS
  float* lf = (float*)p_lds;
  if (lane < 16) {
#pragma unroll
    for (int qt = 0; qt < 4; ++qt)
      lf[wave * 64 + qt * 16 + lane] = lp[qt];
  }
  __syncthreads();
  float lsum = 0.f;
#pragma unroll
  for (int w = 0; w < 8; ++w) lsum += lf[w * 64 + lane];
  const float li = 1.f / lsum;
  const float g  = gptr[0];

  // out[(b*64+c)*4096 + qg*64 + qq]: lanes vary qq -> 256B coalesced stores
#pragma unroll
  for (int r = 0; r < 8; ++r) {
    const int c = wave * 8 + r;
    const size_t off = ((size_t)(b * 64 + c)) * 4096 + (size_t)qg * 64 + lane;
    out[off] = g * (o[r] * li) + xr[r];
  }
}

// ---------------------------------------------------------------------------
extern "C" void kernel_launch(void* const* d_in, const int* in_sizes, int n_in,
                              void* d_out, int out_size, void* d_ws, size_t ws_size,
                              hipStream_t stream)
{
  const float* x  = (const float*)d_in[0];
  const float* Wq = (const float*)d_in[1];
  const float* bq = (const float*)d_in[2];
  const float* Wk = (const float*)d_in[3];
  const float* bk = (const float*)d_in[4];
  const float* Wv = (const float*)d_in[5];
  const float* bv = (const float*)d_in[6];
  const float* g  = (const float*)d_in[7];

  unsigned short* ws = (unsigned short*)d_ws;
  unsigned short* qb = ws;                 // 4*4096*16 bf16 = 512 KB
  unsigned short* kb = ws + 262144;        // 512 KB
  unsigned short* vb = ws + 524288;        // 4*64*4096 bf16 = 2 MB
  float* ob = (float*)d_out;

  hipLaunchKernelGGL(qkv_onepass, dim3(64, 4), dim3(512), 0, stream,
                     x, Wq, bq, Wk, bk, Wv, bv, qb, kb, vb);
  hipLaunchKernelGGL(flash_fused, dim3(64, 4), dim3(512), 0, stream,
                     qb, kb, vb, x, g, ob);
}